// Round 8
// baseline (87.048 us; speedup 1.0000x reference)
//
#include <hip/hip_runtime.h>
#include <cmath>

#define NV    8     // variables
#define NM    42    // coefficients per variable (degree + p - 1)
#define NK    46    // knots per variable (degree + 2p)
#define TOT_C (NM * NV)   // 336
#define LDS_STRIDE 48     // per-v row stride for sc (NM=42 rounded up)

typedef float f32x4 __attribute__((ext_vector_type(4)));

// ---------------------------------------------------------------------------
// Single fused kernel, LIGHT prologue (vs round-6's failed heavy one):
// only wave 0 computes the parameter prep -- softplus into transposed LDS
// (6 rounds x 64 lanes), then lanes 0..7 serially cumsum their v-row in
// registers (consecutive LDS addresses -> b128-fusable reads). Exactly ONE
// __syncthreads. Other 7 waves go straight to the barrier. Eliminates the
// prep kernel launch, the stream-dependency bubble, and the d_ws round-trip.
//
// Eval: uniform knots -> cardinal B-spline form.
//   u = (x - t0)/d - k
//   y  = c0*B0 + c1*B1 + c2*B2 + c3*B3            (uniform cubic basis)
//   dy = (w0*(c1-c0) + w1*(c2-c1) + w2*(c3-c2))/d (q array eliminated:
//        on the uniform grid q_j = (c_{j+1}-c_j)/d)
// 8 elements/thread = one full v=0..7 group: v compile-time per slot,
// st0/sinvd same-address broadcasts, 16 B/lane nontemporal global I/O.
// ---------------------------------------------------------------------------
template <int V>
__device__ __forceinline__ void eval_one(float xv,
                                         const float* __restrict__ sc,
                                         const float* __restrict__ st0,
                                         const float* __restrict__ sinvd,
                                         float& yv, float& ldv) {
    float invd = sinvd[V];
    float f = (xv - st0[V]) * invd;
    int k = (int)floorf(f);
    k = min(max(k, 3), NK - 5);          // clip to [p, K-p-2] = [3, 41]
    float u = f - (float)k;              // outside [0,1) only when clamped:
                                         // same polynomial extrapolation as deBoor
    int base = V * LDS_STRIDE + (k - 3);
    float c0 = sc[base], c1 = sc[base + 1], c2 = sc[base + 2], c3 = sc[base + 3];

    float omu = 1.f - u;
    float u2 = u * u,  o2 = omu * omu;
    float u3 = u2 * u, o3 = o2 * omu;
    const float k6 = 0.16666666666f;
    float B0 = o3 * k6;
    float B3 = u3 * k6;
    float B1 = (3.f * u3 - 6.f * u2 + 4.f) * k6;
    float B2 = 1.f - B0 - B1 - B3;       // partition of unity
    yv = fmaf(B0, c0, fmaf(B1, c1, fmaf(B2, c2, B3 * c3)));

    float w0 = 0.5f * o2, w2 = 0.5f * u2, w1 = 1.f - w0 - w2;
    float dy = fmaf(w0, c1 - c0, fmaf(w1, c2 - c1, w2 * (c3 - c2))) * invd;
    ldv = __logf(dy);
}

__global__ __launch_bounds__(256) void fused_kernel(
        const float* __restrict__ x,
        const float* __restrict__ raw,
        const float* __restrict__ knots,
        float* __restrict__ y_out,
        float* __restrict__ ld_out,
        int total) {
    __shared__ float sc[NV * LDS_STRIDE];
    __shared__ float st0[NV];
    __shared__ float sinvd[NV];
    int tid = threadIdx.x;

    if (tid < 64) {                      // wave 0 only: light prep
        #pragma unroll
        for (int r = 0; r < 6; ++r) {
            int idx = tid + r * 64;
            if (idx < TOT_C) {
                int j = idx >> 3, v = idx & 7;
                float rr = raw[idx];
                float inc;
                if (j == 0) {
                    inc = rr;            // first row: no softplus
                } else {
                    inc = (rr > 0.f) ? (rr + log1pf(expf(-rr))) : log1pf(expf(rr));
                }
                sc[v * LDS_STRIDE + j] = inc;
            }
        }
        if (tid < NV) {
            float t0 = knots[tid];
            st0[tid] = t0;
            sinvd[tid] = 1.0f / (knots[NV + tid] - t0);
        }
        // lanes 0..7: serial cumsum of own v-row (same-wave LDS ops are
        // ordered, so the softplus writes above are visible here)
        if (tid < NV) {
            int base = tid * LDS_STRIDE;
            float acc = 0.f;
            #pragma unroll
            for (int j = 0; j < NM; ++j) {
                acc += sc[base + j];
                sc[base + j] = acc;
            }
        }
    }
    __syncthreads();                     // the ONE barrier

    int t = blockIdx.x * 256 + tid;
    int i0 = t * 8;                      // i0 % 8 == 0  ->  v = slot index
    if (i0 + 7 < total) {
        f32x4 xa = __builtin_nontemporal_load((const f32x4*)(x + i0));
        f32x4 xb = __builtin_nontemporal_load((const f32x4*)(x + i0 + 4));
        float y0,y1,y2,y3,y4,y5,y6,y7, l0,l1,l2,l3,l4,l5,l6,l7;
        eval_one<0>(xa.x, sc, st0, sinvd, y0, l0);
        eval_one<1>(xa.y, sc, st0, sinvd, y1, l1);
        eval_one<2>(xa.z, sc, st0, sinvd, y2, l2);
        eval_one<3>(xa.w, sc, st0, sinvd, y3, l3);
        eval_one<4>(xb.x, sc, st0, sinvd, y4, l4);
        eval_one<5>(xb.y, sc, st0, sinvd, y5, l5);
        eval_one<6>(xb.z, sc, st0, sinvd, y6, l6);
        eval_one<7>(xb.w, sc, st0, sinvd, y7, l7);
        f32x4 ya = {y0, y1, y2, y3}, yb = {y4, y5, y6, y7};
        f32x4 la = {l0, l1, l2, l3}, lb = {l4, l5, l6, l7};
        __builtin_nontemporal_store(ya, (f32x4*)(y_out + i0));
        __builtin_nontemporal_store(yb, (f32x4*)(y_out + i0 + 4));
        __builtin_nontemporal_store(la, (f32x4*)(ld_out + i0));
        __builtin_nontemporal_store(lb, (f32x4*)(ld_out + i0 + 4));
    } else {
        for (int i = i0; i < total; ++i) {
            // generic-v scalar tail (total % 8 == 0 in practice: never taken)
            int v = i & 7;
            float invd = sinvd[v];
            float f = (x[i] - st0[v]) * invd;
            int k = (int)floorf(f);
            k = min(max(k, 3), NK - 5);
            float u = f - (float)k;
            int base = v * LDS_STRIDE + (k - 3);
            float c0 = sc[base], c1 = sc[base + 1], c2 = sc[base + 2], c3 = sc[base + 3];
            float omu = 1.f - u;
            float u2 = u * u,  o2 = omu * omu;
            float u3 = u2 * u, o3 = o2 * omu;
            const float k6 = 0.16666666666f;
            float B0 = o3 * k6, B3 = u3 * k6;
            float B1 = (3.f * u3 - 6.f * u2 + 4.f) * k6;
            float B2 = 1.f - B0 - B1 - B3;
            y_out[i] = fmaf(B0, c0, fmaf(B1, c1, fmaf(B2, c2, B3 * c3)));
            float w0 = 0.5f * o2, w2 = 0.5f * u2, w1 = 1.f - w0 - w2;
            ld_out[i] = __logf(fmaf(w0, c1 - c0, fmaf(w1, c2 - c1, w2 * (c3 - c2))) * invd);
        }
    }
}

extern "C" void kernel_launch(void* const* d_in, const int* in_sizes, int n_in,
                              void* d_out, int out_size, void* d_ws, size_t ws_size,
                              hipStream_t stream) {
    const float* x     = (const float*)d_in[0];
    const float* raw   = (const float*)d_in[1];
    const float* knots = (const float*)d_in[2];

    int total = in_sizes[0];             // N*V = 4,000,000
    float* y_out  = (float*)d_out;
    float* ld_out = y_out + total;

    int nthreads = (total + 7) / 8;
    int blocks = (nthreads + 255) / 256;
    fused_kernel<<<blocks, 256, 0, stream>>>(x, raw, knots, y_out, ld_out, total);
}

// Round 9
// 82.319 us; speedup vs baseline: 1.0574x; 1.0574x over previous
//
#include <hip/hip_runtime.h>
#include <cmath>

#define NV    8     // variables
#define NM    42    // coefficients per variable (degree + p - 1)
#define NK    46    // knots per variable (degree + 2p)
#define TOT_C (NM * NV)   // 336
#define LDS_STRIDE 48     // per-v row stride for sc/sq (NM=42 rounded up)

typedef float f32x4 __attribute__((ext_vector_type(4)));  // clang vector: OK for nontemporal builtins

// ---------------------------------------------------------------------------
// BEST-MEASURED STRUCTURE (round 5, 81.7 us): two kernels.
// Fusion attempts (per-block redundant prep, heavy r6 / light r8) both
// regressed: per-block prep is a latency chain paid by every block, worse
// than one tiny prep dispatch + launch bubble.
//
// Prep (parallel): incr = [raw[0], softplus(raw[1:])]; c = cumsum(incr) via
// Hillis-Steele scan in LDS; q[j] = 3*(c[j+1]-c[j]) / (t[j+4]-t[j+1]).
// One block, 384 threads, ~2 µs.
// ---------------------------------------------------------------------------
__global__ void prep_kernel(const float* __restrict__ raw,
                            const float* __restrict__ knots,
                            float* __restrict__ c,
                            float* __restrict__ q) {
    __shared__ float s[TOT_C];
    int tid = threadIdx.x;
    if (tid < TOT_C) {
        float r = raw[tid];
        float inc;
        if (tid < NV) {
            inc = r;                      // first row: no softplus
        } else {
            inc = (r > 0.f) ? (r + log1pf(expf(-r))) : log1pf(expf(r));
        }
        s[tid] = inc;
    }
    __syncthreads();
    for (int off = 1; off < NM; off <<= 1) {
        float val = 0.f;
        if (tid < TOT_C) {
            int j = tid >> 3;
            val = s[tid] + ((j >= off) ? s[tid - off * NV] : 0.f);
        }
        __syncthreads();
        if (tid < TOT_C) s[tid] = val;
        __syncthreads();
    }
    if (tid < TOT_C) {
        int j = tid >> 3, v = tid & 7;
        float cj = s[tid];
        c[tid] = cj;
        float qj = 0.f;                  // q[NM-1] padding, never read
        if (j < NM - 1) {
            float cn = s[tid + NV];
            qj = 3.f * (cn - cj) / (knots[(j + 4) * NV + v] - knots[(j + 1) * NV + v]);
        }
        q[tid] = qj;
    }
}

// ---------------------------------------------------------------------------
// Eval: uniform knots -> cardinal B-spline form.
//   u = (x - t0)/d - k;  y = sum c[k-3+j]*B3_j(u);  dy = sum q[k-3+j]*B2_j(u)
// 4 elements/thread, 16 B/lane global I/O, LDS transposed to s[v*48 + j] so
// per-element c/q gathers are at consecutive addresses (ds_read2-fusable)
// and banks (16v+k)%32 stay uniform under random k.
// Memory-bound: 48 MB streaming (16 read + 32 write) ~= 8 us BW floor.
// ---------------------------------------------------------------------------
__device__ __forceinline__ void eval_one(float xv, int v,
                                         const float* __restrict__ sc,
                                         const float* __restrict__ sq,
                                         const float* __restrict__ st0,
                                         const float* __restrict__ sinvd,
                                         float& yv, float& ldv) {
    float f = (xv - st0[v]) * sinvd[v];
    int k = (int)floorf(f);
    k = min(max(k, 3), NK - 5);          // clip to [p, K-p-2] = [3, 41]
    float u = f - (float)k;              // outside [0,1) only when clamped:
                                         // same polynomial extrapolation as deBoor
    int base = v * LDS_STRIDE + (k - 3);
    float c0 = sc[base], c1 = sc[base + 1], c2 = sc[base + 2], c3 = sc[base + 3];
    float q0 = sq[base], q1 = sq[base + 1], q2 = sq[base + 2];

    float omu = 1.f - u;
    float u2 = u * u,  o2 = omu * omu;
    float u3 = u2 * u, o3 = o2 * omu;
    const float k6 = 0.16666666666f;
    float B0 = o3 * k6;
    float B3 = u3 * k6;
    float B1 = (3.f * u3 - 6.f * u2 + 4.f) * k6;
    float B2 = 1.f - B0 - B1 - B3;       // partition of unity
    yv = fmaf(B0, c0, fmaf(B1, c1, fmaf(B2, c2, B3 * c3)));

    float w0 = 0.5f * o2, w2 = 0.5f * u2, w1 = 1.f - w0 - w2;
    ldv = __logf(fmaf(w0, q0, fmaf(w1, q1, w2 * q2)));
}

__global__ __launch_bounds__(256) void eval_kernel(
        const float* __restrict__ x,
        const float* __restrict__ knots,
        const float* __restrict__ c,
        const float* __restrict__ q,
        float* __restrict__ y_out,
        float* __restrict__ ld_out,
        int total) {
    __shared__ float sc[NV * LDS_STRIDE];
    __shared__ float sq[NV * LDS_STRIDE];
    __shared__ float st0[NV];
    __shared__ float sinvd[NV];
    int tid = threadIdx.x;
    for (int idx = tid; idx < TOT_C; idx += 256) {
        int j = idx >> 3, v = idx & 7;
        sc[v * LDS_STRIDE + j] = c[idx];
        sq[v * LDS_STRIDE + j] = q[idx];
    }
    if (tid < NV) {
        float t0 = knots[tid];
        st0[tid] = t0;
        sinvd[tid] = 1.0f / (knots[NV + tid] - t0);
    }
    __syncthreads();

    int t = blockIdx.x * 256 + tid;
    int i0 = t * 4;
    if (i0 + 3 < total) {
        f32x4 xv = *(const f32x4*)(x + i0);
        int v0 = i0 & (NV - 1);
        float y0, y1, y2, y3, l0, l1, l2, l3;
        eval_one(xv.x, v0,     sc, sq, st0, sinvd, y0, l0);
        eval_one(xv.y, v0 + 1, sc, sq, st0, sinvd, y1, l1);
        eval_one(xv.z, v0 + 2, sc, sq, st0, sinvd, y2, l2);
        eval_one(xv.w, v0 + 3, sc, sq, st0, sinvd, y3, l3);
        f32x4 yv = {y0, y1, y2, y3};
        f32x4 lv = {l0, l1, l2, l3};
        __builtin_nontemporal_store(yv, (f32x4*)(y_out + i0));
        __builtin_nontemporal_store(lv, (f32x4*)(ld_out + i0));
    } else {
        for (int i = i0; i < total; ++i) {
            float yv, lv;
            eval_one(x[i], i & (NV - 1), sc, sq, st0, sinvd, yv, lv);
            y_out[i]  = yv;
            ld_out[i] = lv;
        }
    }
}

extern "C" void kernel_launch(void* const* d_in, const int* in_sizes, int n_in,
                              void* d_out, int out_size, void* d_ws, size_t ws_size,
                              hipStream_t stream) {
    const float* x     = (const float*)d_in[0];
    const float* raw   = (const float*)d_in[1];
    const float* knots = (const float*)d_in[2];

    float* c = (float*)d_ws;             // 336 floats
    float* q = c + TOT_C;                // 336 floats

    int total = in_sizes[0];             // N*V = 4,000,000
    float* y_out  = (float*)d_out;
    float* ld_out = y_out + total;

    prep_kernel<<<1, 384, 0, stream>>>(raw, knots, c, q);
    int nthreads = (total + 3) / 4;
    int blocks = (nthreads + 255) / 256;
    eval_kernel<<<blocks, 256, 0, stream>>>(x, knots, c, q, y_out, ld_out, total);
}